// Round 5
// baseline (3221.276 us; speedup 1.0000x reference)
//
#include <hip/hip_runtime.h>

#define NN 50000
#define NE 800000
#define EPSV 1e-5f

// ws layout: h [NN*128] f32 | st [1024] f32.  y lives in d_out until k_final.
#define WS_NEEDED ((size_t)(NN * 128 + 1024) * 4)

// Sentinel: ws too small -> fill out with 2.0f (distinct absmax signature ~8.5).
__global__ void k_fallback(float* __restrict__ out) {
  int i = blockIdx.x * 256 + threadIdx.x;
  if (i < NN * 128) out[i] = 2.0f;
}

// mode: 1 = int64 (odd 32-bit words of first 32 values all zero), 0 = int32.
__global__ void k_detect(const int* __restrict__ ei, int* __restrict__ mode) {
  if (threadIdx.x == 0) {
    int all0 = 1;
    for (int i = 1; i < 64; i += 2) all0 &= (ei[i] == 0);
    *mode = all0;
  }
}

__device__ __forceinline__ void load_edge(const int* __restrict__ ei, int m, int e,
                                          int& src, int& dst) {
  if (m) { src = ei[e << 1]; dst = ei[(NE + e) << 1]; }
  else   { src = ei[e];      dst = ei[NE + e]; }
  src = min(max(src, 0), NN - 1);  // never fault even if decode is wrong
  dst = min(max(dst, 0), NN - 1);
}

// y[n] = x[n] @ Wrel ; h[n] = x[n] @ Wroot   (K=64; bias cancels in BN)
// One 32 KB LDS weight buffer, two passes. 8 nodes/block, 32 thr/node, 4 out/thr.
__global__ __launch_bounds__(256) void k_gemm_a(
    const float* __restrict__ x, const float* __restrict__ Wrel,
    const float* __restrict__ Wroot, float* __restrict__ y, float* __restrict__ h) {
  __shared__ float w[64 * 128];  // 32 KB
  const int tid = threadIdx.x;
  const int nd = tid >> 5;
  const int j4 = (tid & 31) << 2;
  const int n = blockIdx.x * 8 + nd;
  const float* xp = x + n * 64;
  for (int pass = 0; pass < 2; ++pass) {
    const float* W = pass ? Wroot : Wrel;
    __syncthreads();
    for (int i = tid; i < 8192; i += 256) w[i] = W[i];
    __syncthreads();
    float a0 = 0.f, a1 = 0.f, a2 = 0.f, a3 = 0.f;
#pragma unroll 4
    for (int k = 0; k < 64; ++k) {
      float xv = xp[k];
      float4 wv = *(const float4*)&w[k * 128 + j4];
      a0 += xv * wv.x; a1 += xv * wv.y; a2 += xv * wv.z; a3 += xv * wv.w;
    }
    float* dstp = pass ? h : y;
    *(float4*)&dstp[n * 128 + j4] = make_float4(a0, a1, a2, a3);
  }
}

// h[dst] += y[src]   (128 feats/edge, 32 threads/edge, float4 slices)
__global__ __launch_bounds__(256) void k_scatter(
    const float* __restrict__ y, const int* __restrict__ ei,
    const int* __restrict__ mode, float* __restrict__ h) {
  int tid = blockIdx.x * 256 + threadIdx.x;
  int e = tid >> 5;
  int f4 = (tid & 31) << 2;
  int src, dst;
  load_edge(ei, *mode, e, src, dst);
  float4 v = *(const float4*)&y[src * 128 + f4];
  float* ap = h + dst * 128 + f4;
  atomicAdd(ap + 0, v.x);
  atomicAdd(ap + 1, v.y);
  atomicAdd(ap + 2, v.z);
  atomicAdd(ap + 3, v.w);
}

// BN stats -> scale/shift. 8 blocks; block b owns channels [16b, 16b+16). No atomics.
__global__ __launch_bounds__(256) void k_stats(
    const float* __restrict__ h, const float* __restrict__ gamma,
    const float* __restrict__ beta, float* __restrict__ scale,
    float* __restrict__ shift) {
  const int b = blockIdx.x;  // 0..7
  const int t = threadIdx.x;
  float s[16], q[16];
#pragma unroll
  for (int i = 0; i < 16; ++i) { s[i] = 0.f; q[i] = 0.f; }
  for (int n = t; n < NN; n += 256) {
    const float* p = h + n * 128 + b * 16;
#pragma unroll
    for (int i = 0; i < 4; ++i) {
      float4 v = *(const float4*)(p + i * 4);
      s[i * 4 + 0] += v.x; q[i * 4 + 0] += v.x * v.x;
      s[i * 4 + 1] += v.y; q[i * 4 + 1] += v.y * v.y;
      s[i * 4 + 2] += v.z; q[i * 4 + 2] += v.z * v.z;
      s[i * 4 + 3] += v.w; q[i * 4 + 3] += v.w * v.w;
    }
  }
#pragma unroll
  for (int off = 32; off > 0; off >>= 1) {
#pragma unroll
    for (int i = 0; i < 16; ++i) {
      s[i] += __shfl_down(s[i], off);
      q[i] += __shfl_down(q[i], off);
    }
  }
  __shared__ float ls[4][16], lq[4][16];
  const int wave = t >> 6, lane = t & 63;
  if (lane == 0) {
#pragma unroll
    for (int i = 0; i < 16; ++i) { ls[wave][i] = s[i]; lq[wave][i] = q[i]; }
  }
  __syncthreads();
  if (t < 16) {
    float S = 0.f, Q = 0.f;
#pragma unroll
    for (int w = 0; w < 4; ++w) { S += ls[w][t]; Q += lq[w][t]; }
    float mean = S * (1.0f / NN);
    float var = fmaxf(Q * (1.0f / NN) - mean * mean, 0.f);
    int c = b * 16 + t;
    float sc = gamma[c] * rsqrtf(var + EPSV);
    scale[c] = sc;
    shift[c] = beta[c] - mean * sc;
  }
}

// t = relu(bn(h[n])):  y[n] = t @ Wrel1 ; h[n] <- t @ Wroot1 (in-place).
// K=128; four 32 KB LDS passes (wrel half0/1, wroot half0/1). h write after barrier.
__global__ __launch_bounds__(256) void k_gemm_b(
    const float* __restrict__ Wrel, const float* __restrict__ Wroot,
    const float* __restrict__ scale, const float* __restrict__ shift,
    float* __restrict__ y, float* h) {
  __shared__ float w[64 * 128];  // 32 KB
  const int tid = threadIdx.x;
  const int nd = tid >> 5;
  const int j4 = (tid & 31) << 2;
  const int n = blockIdx.x * 8 + nd;
  const float* hp = h + n * 128;
  float y0 = 0.f, y1 = 0.f, y2 = 0.f, y3 = 0.f;
  float g0 = 0.f, g1 = 0.f, g2 = 0.f, g3 = 0.f;
  for (int p = 0; p < 4; ++p) {
    const float* W = ((p >> 1) ? Wroot : Wrel) + (p & 1) * 8192;
    const int kb = (p & 1) << 6;
    __syncthreads();
    for (int i = tid; i < 8192; i += 256) w[i] = W[i];
    __syncthreads();
    if (p < 2) {
#pragma unroll 4
      for (int k = 0; k < 64; ++k) {
        float t = fmaxf(hp[kb + k] * scale[kb + k] + shift[kb + k], 0.f);
        float4 wv = *(const float4*)&w[k * 128 + j4];
        y0 += t * wv.x; y1 += t * wv.y; y2 += t * wv.z; y3 += t * wv.w;
      }
    } else {
#pragma unroll 4
      for (int k = 0; k < 64; ++k) {
        float t = fmaxf(hp[kb + k] * scale[kb + k] + shift[kb + k], 0.f);
        float4 wv = *(const float4*)&w[k * 128 + j4];
        g0 += t * wv.x; g1 += t * wv.y; g2 += t * wv.z; g3 += t * wv.w;
      }
    }
  }
  __syncthreads();  // all reads of h done before the in-place write
  *(float4*)&y[n * 128 + j4] = make_float4(y0, y1, y2, y3);
  *(float4*)&h[n * 128 + j4] = make_float4(g0, g1, g2, g3);
}

__global__ __launch_bounds__(256) void k_final(
    const float* __restrict__ h, const float* __restrict__ scale,
    const float* __restrict__ shift, float* __restrict__ out) {
  int tid = blockIdx.x * 256 + threadIdx.x;
  int base = tid << 2;
  int f4 = base & 127;
  float4 v = *(const float4*)&h[base];
  float4 sc = *(const float4*)&scale[f4];
  float4 sh = *(const float4*)&shift[f4];
  *(float4*)&out[base] = make_float4(v.x * sc.x + sh.x, v.y * sc.y + sh.y,
                                     v.z * sc.z + sh.z, v.w * sc.w + sh.w);
}

extern "C" void kernel_launch(void* const* d_in, const int* in_sizes, int n_in,
                              void* d_out, int out_size, void* d_ws, size_t ws_size,
                              hipStream_t stream) {
  if (ws_size < WS_NEEDED) {  // diagnosable clean-fail instead of a fault
    k_fallback<<<(NN * 128 + 255) / 256, 256, 0, stream>>>((float*)d_out);
    return;
  }
  const float* x      = (const float*)d_in[0];
  const int*   ei     = (const int*)d_in[1];
  const float* Wrel0  = (const float*)d_in[2];
  // d_in[3] = b_rel0: per-channel constant pre-BN -> cancels in BN, unused
  const float* Wroot0 = (const float*)d_in[4];
  const float* gamma0 = (const float*)d_in[5];
  const float* beta0  = (const float*)d_in[6];
  const float* Wrel1  = (const float*)d_in[7];
  // d_in[8] = b_rel1: unused (cancels in BN)
  const float* Wroot1 = (const float*)d_in[9];
  const float* gamma1 = (const float*)d_in[10];
  const float* beta1  = (const float*)d_in[11];

  float* h = (float*)d_ws;             // NN*128
  float* st = h + NN * 128;            // 1024 floats
  float* scale0 = st;       float* shift0 = st + 128;
  float* scale1 = st + 256; float* shift1 = st + 384;
  int* mode = (int*)(st + 512);
  float* y = (float*)d_out;            // y buffer lives in d_out until k_final

  k_detect<<<1, 64, 0, stream>>>(ei, mode);
  k_gemm_a<<<NN / 8, 256, 0, stream>>>(x, Wrel0, Wroot0, y, h);
  k_scatter<<<(NE * 32) / 256, 256, 0, stream>>>(y, ei, mode, h);
  k_stats<<<8, 256, 0, stream>>>(h, gamma0, beta0, scale0, shift0);
  k_gemm_b<<<NN / 8, 256, 0, stream>>>(Wrel1, Wroot1, scale0, shift0, y, h);
  k_scatter<<<(NE * 32) / 256, 256, 0, stream>>>(y, ei, mode, h);
  k_stats<<<8, 256, 0, stream>>>(h, gamma1, beta1, scale1, shift1);
  k_final<<<(NN * 128) / 1024, 256, 0, stream>>>(h, scale1, shift1, (float*)d_out);
}

// Round 6
// 830.357 us; speedup vs baseline: 3.8794x; 3.8794x over previous
//
#include <hip/hip_runtime.h>

#define NN 50000
#define NE 800000
#define EPSV 1e-5f

// ws: h [NN*128] f32 | st [1024] f32 | deg [NN] i32 | cur [NN] i32 | csr [NE] i32
#define WS_NEEDED ((size_t)(NN * 128 + 1024 + NN + NN + NE) * 4)

// Sentinel: ws too small -> 2.0f fill (distinct absmax signature ~8.5).
__global__ void k_fallback(float* __restrict__ out) {
  int i = blockIdx.x * 256 + threadIdx.x;
  if (i < NN * 128) out[i] = 2.0f;
}

// mode: 1 = int64 (odd 32-bit words of first 32 values all zero), 0 = int32.
__global__ void k_detect(const int* __restrict__ ei, int* __restrict__ mode) {
  if (threadIdx.x == 0) {
    int all0 = 1;
    for (int i = 1; i < 64; i += 2) all0 &= (ei[i] == 0);
    *mode = all0;
  }
}

__device__ __forceinline__ void load_edge(const int* __restrict__ ei, int m, int e,
                                          int& src, int& dst) {
  if (m) { src = ei[e << 1]; dst = ei[(NE + e) << 1]; }
  else   { src = ei[e];      dst = ei[NE + e]; }
  src = min(max(src, 0), NN - 1);
  dst = min(max(dst, 0), NN - 1);
}

// Degree histogram over dst.
__global__ __launch_bounds__(256) void k_hist(
    const int* __restrict__ ei, const int* __restrict__ mode, int* __restrict__ deg) {
  int e = blockIdx.x * 256 + threadIdx.x;
  int src, dst;
  load_edge(ei, *mode, e, src, dst);
  atomicAdd(&deg[dst], 1);
}

// Exclusive prefix scan of deg -> cur. One block, 1024 threads.
__global__ __launch_bounds__(1024) void k_scan(
    const int* __restrict__ deg, int* __restrict__ cur) {
  __shared__ int part[1024];
  const int t = threadIdx.x;
  const int CH = (NN + 1023) / 1024;  // 49
  const int base = t * CH;
  int s = 0;
  for (int i = 0; i < CH; ++i) {
    int idx = base + i;
    if (idx < NN) s += deg[idx];
  }
  part[t] = s;
  __syncthreads();
  for (int off = 1; off < 1024; off <<= 1) {
    int add = (t >= off) ? part[t - off] : 0;
    __syncthreads();
    part[t] += add;
    __syncthreads();
  }
  int run = part[t] - s;  // exclusive offset of this chunk
  for (int i = 0; i < CH; ++i) {
    int idx = base + i;
    if (idx < NN) { cur[idx] = run; run += deg[idx]; }
  }
}

// Place src ids into CSR buckets; afterwards cur[n] == end offset of node n.
__global__ __launch_bounds__(256) void k_place(
    const int* __restrict__ ei, const int* __restrict__ mode,
    int* __restrict__ cur, int* __restrict__ csr) {
  int e = blockIdx.x * 256 + threadIdx.x;
  int src, dst;
  load_edge(ei, *mode, e, src, dst);
  int pos = atomicAdd(&cur[dst], 1);
  csr[pos] = src;
}

// y[n] = x[n] @ Wrel ; h[n] = x[n] @ Wroot   (K=64; bias cancels in BN)
__global__ __launch_bounds__(256) void k_gemm_a(
    const float* __restrict__ x, const float* __restrict__ Wrel,
    const float* __restrict__ Wroot, float* __restrict__ y, float* __restrict__ h) {
  __shared__ float w[64 * 128];  // 32 KB
  const int tid = threadIdx.x;
  const int nd = tid >> 5;
  const int j4 = (tid & 31) << 2;
  const int n = blockIdx.x * 8 + nd;
  const float* xp = x + n * 64;
  for (int pass = 0; pass < 2; ++pass) {
    const float* W = pass ? Wroot : Wrel;
    __syncthreads();
    for (int i = tid; i < 8192; i += 256) w[i] = W[i];
    __syncthreads();
    float a0 = 0.f, a1 = 0.f, a2 = 0.f, a3 = 0.f;
#pragma unroll 4
    for (int k = 0; k < 64; ++k) {
      float xv = xp[k];
      float4 wv = *(const float4*)&w[k * 128 + j4];
      a0 += xv * wv.x; a1 += xv * wv.y; a2 += xv * wv.z; a3 += xv * wv.w;
    }
    float* dstp = pass ? h : y;
    *(float4*)&dstp[n * 128 + j4] = make_float4(a0, a1, a2, a3);
  }
}

// h[n] += sum over incoming edges of y[src]. 32 lanes/node, float4/lane. No atomics.
__global__ __launch_bounds__(256) void k_gather(
    const float* __restrict__ y, const int* __restrict__ csr,
    const int* __restrict__ cur, const int* __restrict__ deg,
    float* __restrict__ h) {
  int tid = blockIdx.x * 256 + threadIdx.x;
  int n = tid >> 5;
  int f4 = (tid & 31) << 2;
  int end = cur[n];
  int i = end - deg[n];
  float4 a0 = *(const float4*)&h[n * 128 + f4];
  float4 a1 = make_float4(0.f, 0.f, 0.f, 0.f);
  for (; i + 1 < end; i += 2) {
    int s0 = csr[i], s1 = csr[i + 1];
    float4 v0 = *(const float4*)&y[s0 * 128 + f4];
    float4 v1 = *(const float4*)&y[s1 * 128 + f4];
    a0.x += v0.x; a0.y += v0.y; a0.z += v0.z; a0.w += v0.w;
    a1.x += v1.x; a1.y += v1.y; a1.z += v1.z; a1.w += v1.w;
  }
  if (i < end) {
    int s0 = csr[i];
    float4 v0 = *(const float4*)&y[s0 * 128 + f4];
    a0.x += v0.x; a0.y += v0.y; a0.z += v0.z; a0.w += v0.w;
  }
  *(float4*)&h[n * 128 + f4] =
      make_float4(a0.x + a1.x, a0.y + a1.y, a0.z + a1.z, a0.w + a1.w);
}

// BN stats -> scale/shift. 8 blocks; block b owns channels [16b, 16b+16).
__global__ __launch_bounds__(256) void k_stats(
    const float* __restrict__ h, const float* __restrict__ gamma,
    const float* __restrict__ beta, float* __restrict__ scale,
    float* __restrict__ shift) {
  const int b = blockIdx.x;
  const int t = threadIdx.x;
  float s[16], q[16];
#pragma unroll
  for (int i = 0; i < 16; ++i) { s[i] = 0.f; q[i] = 0.f; }
  for (int n = t; n < NN; n += 256) {
    const float* p = h + n * 128 + b * 16;
#pragma unroll
    for (int i = 0; i < 4; ++i) {
      float4 v = *(const float4*)(p + i * 4);
      s[i * 4 + 0] += v.x; q[i * 4 + 0] += v.x * v.x;
      s[i * 4 + 1] += v.y; q[i * 4 + 1] += v.y * v.y;
      s[i * 4 + 2] += v.z; q[i * 4 + 2] += v.z * v.z;
      s[i * 4 + 3] += v.w; q[i * 4 + 3] += v.w * v.w;
    }
  }
#pragma unroll
  for (int off = 32; off > 0; off >>= 1) {
#pragma unroll
    for (int i = 0; i < 16; ++i) {
      s[i] += __shfl_down(s[i], off);
      q[i] += __shfl_down(q[i], off);
    }
  }
  __shared__ float ls[4][16], lq[4][16];
  const int wave = t >> 6, lane = t & 63;
  if (lane == 0) {
#pragma unroll
    for (int i = 0; i < 16; ++i) { ls[wave][i] = s[i]; lq[wave][i] = q[i]; }
  }
  __syncthreads();
  if (t < 16) {
    float S = 0.f, Q = 0.f;
#pragma unroll
    for (int w = 0; w < 4; ++w) { S += ls[w][t]; Q += lq[w][t]; }
    float mean = S * (1.0f / NN);
    float var = fmaxf(Q * (1.0f / NN) - mean * mean, 0.f);
    int c = b * 16 + t;
    float sc = gamma[c] * rsqrtf(var + EPSV);
    scale[c] = sc;
    shift[c] = beta[c] - mean * sc;
  }
}

// t = relu(bn(h[n])):  y[n] = t @ Wrel1 ; h[n] <- t @ Wroot1 (in-place, post-barrier).
__global__ __launch_bounds__(256) void k_gemm_b(
    const float* __restrict__ Wrel, const float* __restrict__ Wroot,
    const float* __restrict__ scale, const float* __restrict__ shift,
    float* __restrict__ y, float* h) {
  __shared__ float w[64 * 128];  // 32 KB
  const int tid = threadIdx.x;
  const int nd = tid >> 5;
  const int j4 = (tid & 31) << 2;
  const int n = blockIdx.x * 8 + nd;
  const float* hp = h + n * 128;
  float y0 = 0.f, y1 = 0.f, y2 = 0.f, y3 = 0.f;
  float g0 = 0.f, g1 = 0.f, g2 = 0.f, g3 = 0.f;
  for (int p = 0; p < 4; ++p) {
    const float* W = ((p >> 1) ? Wroot : Wrel) + (p & 1) * 8192;
    const int kb = (p & 1) << 6;
    __syncthreads();
    for (int i = tid; i < 8192; i += 256) w[i] = W[i];
    __syncthreads();
    if (p < 2) {
#pragma unroll 4
      for (int k = 0; k < 64; ++k) {
        float t = fmaxf(hp[kb + k] * scale[kb + k] + shift[kb + k], 0.f);
        float4 wv = *(const float4*)&w[k * 128 + j4];
        y0 += t * wv.x; y1 += t * wv.y; y2 += t * wv.z; y3 += t * wv.w;
      }
    } else {
#pragma unroll 4
      for (int k = 0; k < 64; ++k) {
        float t = fmaxf(hp[kb + k] * scale[kb + k] + shift[kb + k], 0.f);
        float4 wv = *(const float4*)&w[k * 128 + j4];
        g0 += t * wv.x; g1 += t * wv.y; g2 += t * wv.z; g3 += t * wv.w;
      }
    }
  }
  __syncthreads();  // all reads of h complete before in-place write
  *(float4*)&y[n * 128 + j4] = make_float4(y0, y1, y2, y3);
  *(float4*)&h[n * 128 + j4] = make_float4(g0, g1, g2, g3);
}

__global__ __launch_bounds__(256) void k_final(
    const float* __restrict__ h, const float* __restrict__ scale,
    const float* __restrict__ shift, float* __restrict__ out) {
  int tid = blockIdx.x * 256 + threadIdx.x;
  int base = tid << 2;
  int f4 = base & 127;
  float4 v = *(const float4*)&h[base];
  float4 sc = *(const float4*)&scale[f4];
  float4 sh = *(const float4*)&shift[f4];
  *(float4*)&out[base] = make_float4(v.x * sc.x + sh.x, v.y * sc.y + sh.y,
                                     v.z * sc.z + sh.z, v.w * sc.w + sh.w);
}

extern "C" void kernel_launch(void* const* d_in, const int* in_sizes, int n_in,
                              void* d_out, int out_size, void* d_ws, size_t ws_size,
                              hipStream_t stream) {
  if (ws_size < WS_NEEDED) {
    k_fallback<<<(NN * 128 + 255) / 256, 256, 0, stream>>>((float*)d_out);
    return;
  }
  const float* x      = (const float*)d_in[0];
  const int*   ei     = (const int*)d_in[1];
  const float* Wrel0  = (const float*)d_in[2];
  // d_in[3] = b_rel0: constant per channel pre-BN -> cancels in BN, unused
  const float* Wroot0 = (const float*)d_in[4];
  const float* gamma0 = (const float*)d_in[5];
  const float* beta0  = (const float*)d_in[6];
  const float* Wrel1  = (const float*)d_in[7];
  // d_in[8] = b_rel1: unused (cancels in BN)
  const float* Wroot1 = (const float*)d_in[9];
  const float* gamma1 = (const float*)d_in[10];
  const float* beta1  = (const float*)d_in[11];

  float* h  = (float*)d_ws;            // NN*128
  float* st = h + NN * 128;            // 1024 floats
  float* scale0 = st;       float* shift0 = st + 128;
  float* scale1 = st + 256; float* shift1 = st + 384;
  int* mode = (int*)(st + 512);
  int* deg = (int*)(st + 1024);        // NN
  int* cur = deg + NN;                 // NN
  int* csr = cur + NN;                 // NE
  float* y = (float*)d_out;            // y lives in d_out until k_final

  hipMemsetAsync(deg, 0, (size_t)NN * 4, stream);
  k_detect<<<1, 64, 0, stream>>>(ei, mode);
  k_hist<<<NE / 256, 256, 0, stream>>>(ei, mode, deg);
  k_scan<<<1, 1024, 0, stream>>>(deg, cur);
  k_place<<<NE / 256, 256, 0, stream>>>(ei, mode, cur, csr);

  k_gemm_a<<<NN / 8, 256, 0, stream>>>(x, Wrel0, Wroot0, y, h);
  k_gather<<<NN / 8, 256, 0, stream>>>(y, csr, cur, deg, h);
  k_stats<<<8, 256, 0, stream>>>(h, gamma0, beta0, scale0, shift0);
  k_gemm_b<<<NN / 8, 256, 0, stream>>>(Wrel1, Wroot1, scale0, shift0, y, h);
  k_gather<<<NN / 8, 256, 0, stream>>>(y, csr, cur, deg, h);
  k_stats<<<8, 256, 0, stream>>>(h, gamma1, beta1, scale1, shift1);
  k_final<<<(NN * 128) / 1024, 256, 0, stream>>>(h, scale1, shift1, (float*)d_out);
}

// Round 7
// 763.495 us; speedup vs baseline: 4.2191x; 1.0876x over previous
//
#include <hip/hip_runtime.h>

#define NN 50000
#define NE 800000
#define EPSV 1e-5f

// ws: h [NN*128] | st [1024] | deg [NN] | cur [NN] | csr [NE] | psum [32768] | pssq [32768]
#define WS_NEEDED ((size_t)(NN * 128 + 1024 + NN + NN + NE + 32768 + 32768) * 4)

__global__ void k_fallback(float* __restrict__ out) {
  int i = blockIdx.x * 256 + threadIdx.x;
  if (i < NN * 128) out[i] = 2.0f;
}

// mode: 1 = int64 (odd 32-bit words of first 32 values all zero), 0 = int32.
__global__ void k_detect(const int* __restrict__ ei, int* __restrict__ mode) {
  if (threadIdx.x == 0) {
    int all0 = 1;
    for (int i = 1; i < 64; i += 2) all0 &= (ei[i] == 0);
    *mode = all0;
  }
}

__device__ __forceinline__ void load_edge(const int* __restrict__ ei, int m, int e,
                                          int& src, int& dst) {
  if (m) { src = ei[e << 1]; dst = ei[(NE + e) << 1]; }
  else   { src = ei[e];      dst = ei[NE + e]; }
  src = min(max(src, 0), NN - 1);
  dst = min(max(dst, 0), NN - 1);
}

__global__ __launch_bounds__(256) void k_hist(
    const int* __restrict__ ei, const int* __restrict__ mode, int* __restrict__ deg) {
  int e = blockIdx.x * 256 + threadIdx.x;
  int src, dst;
  load_edge(ei, *mode, e, src, dst);
  atomicAdd(&deg[dst], 1);
}

// Exclusive prefix scan of deg -> cur. 1024 threads, shfl-based, 2 barriers.
__global__ __launch_bounds__(1024) void k_scan(
    const int* __restrict__ deg, int* __restrict__ cur) {
  const int t = threadIdx.x;
  const int lane = t & 63, wave = t >> 6;
  const int CH = 49;  // 1024*49 = 50176 >= NN
  const int base = t * CH;
  int s = 0;
  for (int i = 0; i < CH; ++i) {
    int idx = base + i;
    if (idx < NN) s += deg[idx];
  }
  // inclusive scan within wave
  int incl = s;
  for (int off = 1; off < 64; off <<= 1) {
    int v = __shfl_up(incl, off);
    if (lane >= off) incl += v;
  }
  __shared__ int wtot[16];
  if (lane == 63) wtot[wave] = incl;
  __syncthreads();
  if (t < 16) {  // exclusive scan of 16 wave totals (lanes 0..15 of wave 0)
    int v = wtot[t];
    int sc = v;
    for (int off = 1; off < 16; off <<= 1) {
      int u = __shfl_up(sc, off);
      if (t >= off) sc += u;
    }
    wtot[t] = sc - v;
  }
  __syncthreads();
  int run = wtot[wave] + incl - s;  // exclusive offset of this thread's chunk
  for (int i = 0; i < CH; ++i) {
    int idx = base + i;
    if (idx < NN) { cur[idx] = run; run += deg[idx]; }
  }
}

// Place src ids into CSR buckets; afterwards cur[n] == end offset of node n.
__global__ __launch_bounds__(256) void k_place(
    const int* __restrict__ ei, const int* __restrict__ mode,
    int* __restrict__ cur, int* __restrict__ csr) {
  int e = blockIdx.x * 256 + threadIdx.x;
  int src, dst;
  load_edge(ei, *mode, e, src, dst);
  int pos = atomicAdd(&cur[dst], 1);
  csr[pos] = src;
}

// y[n] = x[n] @ Wrel ; h[n] = x[n] @ Wroot  (K=64; bias cancels in BN).
// 16 nodes/block; activations staged in LDS (padded stride 68), weights from L2.
__global__ __launch_bounds__(256) void k_gemm_a(
    const float* __restrict__ x, const float* __restrict__ Wrel,
    const float* __restrict__ Wroot, float* __restrict__ y, float* __restrict__ h) {
  __shared__ float xs[16 * 68];
  const int tid = threadIdx.x;
  const int nb = blockIdx.x * 16;
  {  // stage 16 x-rows (1024 floats, one float4/thread)
    int node = tid >> 4, f = (tid & 15) << 2;
    float4 v = *(const float4*)&x[(nb + node) * 64 + f];
    *(float4*)&xs[node * 68 + f] = v;
  }
  __syncthreads();
  const int nd = tid >> 4;
  const int j8 = (tid & 15) << 3;
  float y0 = 0.f, y1 = 0.f, y2 = 0.f, y3 = 0.f, y4 = 0.f, y5 = 0.f, y6 = 0.f, y7 = 0.f;
  float g0 = 0.f, g1 = 0.f, g2 = 0.f, g3 = 0.f, g4 = 0.f, g5 = 0.f, g6 = 0.f, g7 = 0.f;
#pragma unroll 2
  for (int k = 0; k < 64; ++k) {
    float t = xs[nd * 68 + k];
    float4 wr0 = *(const float4*)&Wrel[k * 128 + j8];
    float4 wr1 = *(const float4*)&Wrel[k * 128 + j8 + 4];
    float4 wo0 = *(const float4*)&Wroot[k * 128 + j8];
    float4 wo1 = *(const float4*)&Wroot[k * 128 + j8 + 4];
    y0 += t * wr0.x; y1 += t * wr0.y; y2 += t * wr0.z; y3 += t * wr0.w;
    y4 += t * wr1.x; y5 += t * wr1.y; y6 += t * wr1.z; y7 += t * wr1.w;
    g0 += t * wo0.x; g1 += t * wo0.y; g2 += t * wo0.z; g3 += t * wo0.w;
    g4 += t * wo1.x; g5 += t * wo1.y; g6 += t * wo1.z; g7 += t * wo1.w;
  }
  const int n = nb + nd;
  *(float4*)&y[n * 128 + j8]     = make_float4(y0, y1, y2, y3);
  *(float4*)&y[n * 128 + j8 + 4] = make_float4(y4, y5, y6, y7);
  *(float4*)&h[n * 128 + j8]     = make_float4(g0, g1, g2, g3);
  *(float4*)&h[n * 128 + j8 + 4] = make_float4(g4, g5, g6, g7);
}

// h[n] += sum over incoming edges of y[src]. 32 lanes/node, float4/lane, unroll 4.
__global__ __launch_bounds__(256) void k_gather(
    const float* __restrict__ y, const int* __restrict__ csr,
    const int* __restrict__ cur, const int* __restrict__ deg,
    float* __restrict__ h) {
  int tid = blockIdx.x * 256 + threadIdx.x;
  int n = tid >> 5;
  int f4 = (tid & 31) << 2;
  int end = cur[n];
  int i = end - deg[n];
  float4 a0 = *(const float4*)&h[n * 128 + f4];
  float4 a1 = make_float4(0.f, 0.f, 0.f, 0.f);
  float4 a2 = make_float4(0.f, 0.f, 0.f, 0.f);
  float4 a3 = make_float4(0.f, 0.f, 0.f, 0.f);
  for (; i + 3 < end; i += 4) {
    int s0 = csr[i], s1 = csr[i + 1], s2 = csr[i + 2], s3 = csr[i + 3];
    float4 v0 = *(const float4*)&y[s0 * 128 + f4];
    float4 v1 = *(const float4*)&y[s1 * 128 + f4];
    float4 v2 = *(const float4*)&y[s2 * 128 + f4];
    float4 v3 = *(const float4*)&y[s3 * 128 + f4];
    a0.x += v0.x; a0.y += v0.y; a0.z += v0.z; a0.w += v0.w;
    a1.x += v1.x; a1.y += v1.y; a1.z += v1.z; a1.w += v1.w;
    a2.x += v2.x; a2.y += v2.y; a2.z += v2.z; a2.w += v2.w;
    a3.x += v3.x; a3.y += v3.y; a3.z += v3.z; a3.w += v3.w;
  }
  for (; i < end; ++i) {
    int s0 = csr[i];
    float4 v0 = *(const float4*)&y[s0 * 128 + f4];
    a0.x += v0.x; a0.y += v0.y; a0.z += v0.z; a0.w += v0.w;
  }
  *(float4*)&h[n * 128 + f4] = make_float4(a0.x + a1.x + a2.x + a3.x,
                                           a0.y + a1.y + a2.y + a3.y,
                                           a0.z + a1.z + a2.z + a3.z,
                                           a0.w + a1.w + a2.w + a3.w);
}

// Stage 1: 256 blocks write per-block channel partial sum/sumsq (no atomics).
__global__ __launch_bounds__(256) void k_stats_part(
    const float* __restrict__ h, float* __restrict__ psum, float* __restrict__ pssq) {
  const int p = blockIdx.x;
  const int t = threadIdx.x;
  const int c = t & 127, half = t >> 7;
  float s = 0.f, q = 0.f;
  const int base = p * 196;
  for (int i = half; i < 196; i += 2) {
    int n = base + i;
    if (n < NN) {
      float v = h[n * 128 + c];
      s += v; q += v * v;
    }
  }
  __shared__ float ls[128], lq[128];
  if (half) { ls[c] = s; lq[c] = q; }
  __syncthreads();
  if (!half) {
    psum[p * 128 + c] = s + ls[c];
    pssq[p * 128 + c] = q + lq[c];
  }
}

// Stage 2: reduce 256 partials -> scale/shift.
__global__ __launch_bounds__(128) void k_bnfin(
    const float* __restrict__ psum, const float* __restrict__ pssq,
    const float* __restrict__ gamma, const float* __restrict__ beta,
    float* __restrict__ scale, float* __restrict__ shift) {
  const int c = threadIdx.x;
  float S = 0.f, Q = 0.f;
  for (int p = 0; p < 256; ++p) { S += psum[p * 128 + c]; Q += pssq[p * 128 + c]; }
  float mean = S * (1.0f / NN);
  float var = fmaxf(Q * (1.0f / NN) - mean * mean, 0.f);
  float sc = gamma[c] * rsqrtf(var + EPSV);
  scale[c] = sc;
  shift[c] = beta[c] - mean * sc;
}

// t = relu(bn(h[n])) staged in LDS (pad 132); y[n] = t@Wrel1, h[n] <- t@Wroot1.
// Weights streamed from L2 (131 KB/block). In-place h safe: all reads staged first.
__global__ __launch_bounds__(256) void k_gemm_b(
    const float* __restrict__ Wrel, const float* __restrict__ Wroot,
    const float* __restrict__ scale, const float* __restrict__ shift,
    float* __restrict__ y, float* __restrict__ h) {
  __shared__ float ts[16 * 132];
  const int tid = threadIdx.x;
  const int nb = blockIdx.x * 16;
#pragma unroll
  for (int i = 0; i < 2; ++i) {  // stage 16 rows of relu(bn(h)): 512 float4s
    int q = tid * 2 + i;
    int node = q >> 5, f = (q & 31) << 2;
    float4 v = *(const float4*)&h[(nb + node) * 128 + f];
    float4 sc = *(const float4*)&scale[f];
    float4 sh = *(const float4*)&shift[f];
    *(float4*)&ts[node * 132 + f] =
        make_float4(fmaxf(v.x * sc.x + sh.x, 0.f), fmaxf(v.y * sc.y + sh.y, 0.f),
                    fmaxf(v.z * sc.z + sh.z, 0.f), fmaxf(v.w * sc.w + sh.w, 0.f));
  }
  __syncthreads();
  const int nd = tid >> 4;
  const int j8 = (tid & 15) << 3;
  float y0 = 0.f, y1 = 0.f, y2 = 0.f, y3 = 0.f, y4 = 0.f, y5 = 0.f, y6 = 0.f, y7 = 0.f;
  float g0 = 0.f, g1 = 0.f, g2 = 0.f, g3 = 0.f, g4 = 0.f, g5 = 0.f, g6 = 0.f, g7 = 0.f;
#pragma unroll 2
  for (int k = 0; k < 128; ++k) {
    float t = ts[nd * 132 + k];
    float4 wr0 = *(const float4*)&Wrel[k * 128 + j8];
    float4 wr1 = *(const float4*)&Wrel[k * 128 + j8 + 4];
    float4 wo0 = *(const float4*)&Wroot[k * 128 + j8];
    float4 wo1 = *(const float4*)&Wroot[k * 128 + j8 + 4];
    y0 += t * wr0.x; y1 += t * wr0.y; y2 += t * wr0.z; y3 += t * wr0.w;
    y4 += t * wr1.x; y5 += t * wr1.y; y6 += t * wr1.z; y7 += t * wr1.w;
    g0 += t * wo0.x; g1 += t * wo0.y; g2 += t * wo0.z; g3 += t * wo0.w;
    g4 += t * wo1.x; g5 += t * wo1.y; g6 += t * wo1.z; g7 += t * wo1.w;
  }
  const int n = nb + nd;
  *(float4*)&y[n * 128 + j8]     = make_float4(y0, y1, y2, y3);
  *(float4*)&y[n * 128 + j8 + 4] = make_float4(y4, y5, y6, y7);
  *(float4*)&h[n * 128 + j8]     = make_float4(g0, g1, g2, g3);
  *(float4*)&h[n * 128 + j8 + 4] = make_float4(g4, g5, g6, g7);
}

__global__ __launch_bounds__(256) void k_final(
    const float* __restrict__ h, const float* __restrict__ scale,
    const float* __restrict__ shift, float* __restrict__ out) {
  int tid = blockIdx.x * 256 + threadIdx.x;
  int base = tid << 2;
  int f4 = base & 127;
  float4 v = *(const float4*)&h[base];
  float4 sc = *(const float4*)&scale[f4];
  float4 sh = *(const float4*)&shift[f4];
  *(float4*)&out[base] = make_float4(v.x * sc.x + sh.x, v.y * sc.y + sh.y,
                                     v.z * sc.z + sh.z, v.w * sc.w + sh.w);
}

extern "C" void kernel_launch(void* const* d_in, const int* in_sizes, int n_in,
                              void* d_out, int out_size, void* d_ws, size_t ws_size,
                              hipStream_t stream) {
  if (ws_size < WS_NEEDED) {
    k_fallback<<<(NN * 128 + 255) / 256, 256, 0, stream>>>((float*)d_out);
    return;
  }
  const float* x      = (const float*)d_in[0];
  const int*   ei     = (const int*)d_in[1];
  const float* Wrel0  = (const float*)d_in[2];
  // d_in[3] = b_rel0: constant per channel pre-BN -> cancels in BN, unused
  const float* Wroot0 = (const float*)d_in[4];
  const float* gamma0 = (const float*)d_in[5];
  const float* beta0  = (const float*)d_in[6];
  const float* Wrel1  = (const float*)d_in[7];
  // d_in[8] = b_rel1: unused (cancels in BN)
  const float* Wroot1 = (const float*)d_in[9];
  const float* gamma1 = (const float*)d_in[10];
  const float* beta1  = (const float*)d_in[11];

  float* h  = (float*)d_ws;            // NN*128
  float* st = h + NN * 128;            // 1024 floats
  float* scale0 = st;       float* shift0 = st + 128;
  float* scale1 = st + 256; float* shift1 = st + 384;
  int* mode = (int*)(st + 512);
  int* deg = (int*)(st + 1024);        // NN
  int* cur = deg + NN;                 // NN
  int* csr = cur + NN;                 // NE
  float* psum = (float*)(csr + NE);    // 256*128
  float* pssq = psum + 32768;          // 256*128
  float* y = (float*)d_out;            // y lives in d_out until k_final

  hipMemsetAsync(deg, 0, (size_t)NN * 4, stream);
  k_detect<<<1, 64, 0, stream>>>(ei, mode);
  k_hist<<<NE / 256, 256, 0, stream>>>(ei, mode, deg);
  k_scan<<<1, 1024, 0, stream>>>(deg, cur);
  k_place<<<NE / 256, 256, 0, stream>>>(ei, mode, cur, csr);

  k_gemm_a<<<NN / 16, 256, 0, stream>>>(x, Wrel0, Wroot0, y, h);
  k_gather<<<(NN * 32) / 256, 256, 0, stream>>>(y, csr, cur, deg, h);
  k_stats_part<<<256, 256, 0, stream>>>(h, psum, pssq);
  k_bnfin<<<1, 128, 0, stream>>>(psum, pssq, gamma0, beta0, scale0, shift0);
  k_gemm_b<<<NN / 16, 256, 0, stream>>>(Wrel1, Wroot1, scale0, shift0, y, h);
  k_gather<<<(NN * 32) / 256, 256, 0, stream>>>(y, csr, cur, deg, h);
  k_stats_part<<<256, 256, 0, stream>>>(h, psum, pssq);
  k_bnfin<<<1, 128, 0, stream>>>(psum, pssq, gamma1, beta1, scale1, shift1);
  k_final<<<(NN * 128) / 1024, 256, 0, stream>>>(h, scale1, shift1, (float*)d_out);
}

// Round 8
// 516.589 us; speedup vs baseline: 6.2357x; 1.4780x over previous
//
#include <hip/hip_runtime.h>

#define NN 50000
#define NE 800000
#define EPSV 1e-5f

typedef unsigned int u32;

// ws: aggx/yb [NN*64] | st [1024] | deg [NN] | cur [NN] | csr [NE] | psum/pssq [2*32768]
#define WS_NEEDED ((size_t)(NN * 64 + 1024 + NN + NN + NE + 65536) * 4)

__global__ void k_fallback(float* __restrict__ out) {
  int i = blockIdx.x * 256 + threadIdx.x;
  if (i < NN * 128) out[i] = 2.0f;
}

// mode: 1 = int64 (odd 32-bit words of first 32 values all zero), 0 = int32.
__global__ void k_detect(const int* __restrict__ ei, int* __restrict__ mode) {
  if (threadIdx.x == 0) {
    int all0 = 1;
    for (int i = 1; i < 64; i += 2) all0 &= (ei[i] == 0);
    *mode = all0;
  }
}

__device__ __forceinline__ void load_edge(const int* __restrict__ ei, int m, int e,
                                          int& src, int& dst) {
  if (m) { src = ei[e << 1]; dst = ei[(NE + e) << 1]; }
  else   { src = ei[e];      dst = ei[NE + e]; }
  src = min(max(src, 0), NN - 1);
  dst = min(max(dst, 0), NN - 1);
}

__global__ __launch_bounds__(256) void k_hist(
    const int* __restrict__ ei, const int* __restrict__ mode, int* __restrict__ deg) {
  int e = blockIdx.x * 256 + threadIdx.x;
  int src, dst;
  load_edge(ei, *mode, e, src, dst);
  atomicAdd(&deg[dst], 1);
}

__global__ __launch_bounds__(1024) void k_scan(
    const int* __restrict__ deg, int* __restrict__ cur) {
  const int t = threadIdx.x;
  const int lane = t & 63, wave = t >> 6;
  const int CH = 49;
  const int base = t * CH;
  int s = 0;
  for (int i = 0; i < CH; ++i) {
    int idx = base + i;
    if (idx < NN) s += deg[idx];
  }
  int incl = s;
  for (int off = 1; off < 64; off <<= 1) {
    int v = __shfl_up(incl, off);
    if (lane >= off) incl += v;
  }
  __shared__ int wtot[16];
  if (lane == 63) wtot[wave] = incl;
  __syncthreads();
  if (t < 16) {
    int v = wtot[t];
    int sc = v;
    for (int off = 1; off < 16; off <<= 1) {
      int u = __shfl_up(sc, off);
      if (t >= off) sc += u;
    }
    wtot[t] = sc - v;
  }
  __syncthreads();
  int run = wtot[wave] + incl - s;
  for (int i = 0; i < CH; ++i) {
    int idx = base + i;
    if (idx < NN) { cur[idx] = run; run += deg[idx]; }
  }
}

__global__ __launch_bounds__(256) void k_place(
    const int* __restrict__ ei, const int* __restrict__ mode,
    int* __restrict__ cur, int* __restrict__ csr) {
  int e = blockIdx.x * 256 + threadIdx.x;
  int src, dst;
  load_edge(ei, *mode, e, src, dst);
  int pos = atomicAdd(&cur[dst], 1);
  csr[pos] = src;
}

// aggx[n] = sum over incoming edges of x[src]  (64 ch; 16 lanes/node, float4/lane)
__global__ __launch_bounds__(256) void k_gather_x(
    const float* __restrict__ x, const int* __restrict__ csr,
    const int* __restrict__ cur, const int* __restrict__ deg,
    float* __restrict__ aggx) {
  int tid = blockIdx.x * 256 + threadIdx.x;
  int n = tid >> 4;
  int f4 = (tid & 15) << 2;
  int end = cur[n];
  int i = end - deg[n];
  float4 a = make_float4(0.f, 0.f, 0.f, 0.f);
  float4 b = make_float4(0.f, 0.f, 0.f, 0.f);
  for (; i + 1 < end; i += 2) {
    int s0 = csr[i], s1 = csr[i + 1];
    float4 v0 = *(const float4*)&x[s0 * 64 + f4];
    float4 v1 = *(const float4*)&x[s1 * 64 + f4];
    a.x += v0.x; a.y += v0.y; a.z += v0.z; a.w += v0.w;
    b.x += v1.x; b.y += v1.y; b.z += v1.z; b.w += v1.w;
  }
  if (i < end) {
    int s0 = csr[i];
    float4 v0 = *(const float4*)&x[s0 * 64 + f4];
    a.x += v0.x; a.y += v0.y; a.z += v0.z; a.w += v0.w;
  }
  *(float4*)&aggx[n * 64 + f4] =
      make_float4(a.x + b.x, a.y + b.y, a.z + b.z, a.w + b.w);
}

// h = [aggx | x] @ [Wrel0 ; Wroot0]  (M=NN, K=128, N=128).
// Block: 128 nodes x 128 j; thread: 8 nodes x 8 j (j = tx+16m).
__global__ __launch_bounds__(256) void k_gemm_a(
    const float* __restrict__ x, const float* __restrict__ aggx,
    const float* __restrict__ Wrel, const float* __restrict__ Wroot,
    float* __restrict__ h) {
  __shared__ float As[16 * 132];  // [kk][node], pad 132
  __shared__ float Bs[16 * 128];  // [kk][j]
  const int tid = threadIdx.x;
  const int nb = blockIdx.x * 128;
  const int tx = tid & 15;
  const int ty = tid >> 4;
  float acc[8][8];
#pragma unroll
  for (int i = 0; i < 8; ++i)
#pragma unroll
    for (int m = 0; m < 8; ++m) acc[i][m] = 0.f;

  for (int k0 = 0; k0 < 128; k0 += 16) {
    const float* Asrc = (k0 < 64) ? aggx : x;
    const float* Bsrc = (k0 < 64) ? Wrel : Wroot;
    const int kbase = (k0 < 64) ? k0 : (k0 - 64);
    __syncthreads();
#pragma unroll
    for (int it = 0; it < 2; ++it) {  // A: 128 nodes x 16 k = 512 float4
      int fid = tid + 256 * it;
      int node = fid >> 2, kq = (fid & 3) << 2;
      int n = nb + node;
      float4 v = (n < NN) ? *(const float4*)&Asrc[n * 64 + kbase + kq]
                          : make_float4(0.f, 0.f, 0.f, 0.f);
      As[(kq + 0) * 132 + node] = v.x;
      As[(kq + 1) * 132 + node] = v.y;
      As[(kq + 2) * 132 + node] = v.z;
      As[(kq + 3) * 132 + node] = v.w;
    }
#pragma unroll
    for (int it = 0; it < 2; ++it) {  // B: 16 x 128 = 512 float4
      int fid = tid + 256 * it;
      int kk = fid >> 5, j4 = (fid & 31) << 2;
      *(float4*)&Bs[kk * 128 + j4] = *(const float4*)&Bsrc[(kbase + kk) * 128 + j4];
    }
    __syncthreads();
#pragma unroll 4
    for (int kk = 0; kk < 16; ++kk) {
      float a[8], b[8];
      *(float4*)&a[0] = *(const float4*)&As[kk * 132 + ty * 8];
      *(float4*)&a[4] = *(const float4*)&As[kk * 132 + ty * 8 + 4];
#pragma unroll
      for (int m = 0; m < 8; ++m) b[m] = Bs[kk * 128 + tx + 16 * m];
#pragma unroll
      for (int i = 0; i < 8; ++i)
#pragma unroll
        for (int m = 0; m < 8; ++m) acc[i][m] += a[i] * b[m];
    }
  }
#pragma unroll
  for (int i = 0; i < 8; ++i) {
    int n = nb + ty * 8 + i;
    if (n < NN) {
#pragma unroll
      for (int m = 0; m < 8; ++m) h[n * 128 + tx + 16 * m] = acc[i][m];
    }
  }
}

// Stage 1 BN stats: 256 blocks of per-block channel partials.
__global__ __launch_bounds__(256) void k_stats_part(
    const float* __restrict__ h, float* __restrict__ psum, float* __restrict__ pssq) {
  const int p = blockIdx.x;
  const int t = threadIdx.x;
  const int c = t & 127, half = t >> 7;
  float s = 0.f, q = 0.f;
  const int base = p * 196;
  for (int i = half; i < 196; i += 2) {
    int n = base + i;
    if (n < NN) {
      float v = h[n * 128 + c];
      s += v; q += v * v;
    }
  }
  __shared__ float ls[128], lq[128];
  if (half) { ls[c] = s; lq[c] = q; }
  __syncthreads();
  if (!half) {
    psum[p * 128 + c] = s + ls[c];
    pssq[p * 128 + c] = q + lq[c];
  }
}

__global__ __launch_bounds__(128) void k_bnfin(
    const float* __restrict__ psum, const float* __restrict__ pssq,
    const float* __restrict__ gamma, const float* __restrict__ beta,
    float* __restrict__ scale, float* __restrict__ shift) {
  const int c = threadIdx.x;
  float S = 0.f, Q = 0.f;
  for (int p = 0; p < 256; ++p) { S += psum[p * 128 + c]; Q += pssq[p * 128 + c]; }
  float mean = S * (1.0f / NN);
  float var = fmaxf(Q * (1.0f / NN) - mean * mean, 0.f);
  float sc = gamma[c] * rsqrtf(var + EPSV);
  scale[c] = sc;
  shift[c] = beta[c] - mean * sc;
}

__device__ __forceinline__ u32 pack_bf16(float lo, float hi) {
  union { float f; u32 u; } a, b;
  a.f = lo; b.f = hi;
  u32 ua = a.u + 0x7fffu + ((a.u >> 16) & 1u);
  u32 ub = b.u + 0x7fffu + ((b.u >> 16) & 1u);
  return (ua >> 16) | (ub & 0xffff0000u);
}

// t = relu(bn(h)); yb = bf16(t @ Wrel1) packed; h <- t @ Wroot1 (in place).
// Block: 64 nodes x 256 j; thread: 8 nodes x 8 j (j = tx+32m; m<4 -> yb, m>=4 -> h).
__global__ __launch_bounds__(256) void k_gemm_b(
    const float* __restrict__ Wrel, const float* __restrict__ Wroot,
    const float* __restrict__ scale, const float* __restrict__ shift,
    u32* __restrict__ yb, float* __restrict__ h) {
  __shared__ float As[128 * 68];  // [k][node], pad 68: 34.8 KB
  __shared__ float Bs[16 * 256];  // 16 KB
  const int tid = threadIdx.x;
  const int nb = blockIdx.x * 64;
  const int tx = tid & 31;
  const int ty = tid >> 5;
  // Stage A = relu(bn(h)) transposed. 64 nodes x 32 k-quads = 2048 float4.
#pragma unroll
  for (int it = 0; it < 8; ++it) {
    int fid = tid + 256 * it;
    int node = fid >> 5, kq = (fid & 31) << 2;
    int n = nb + node;
    float4 v = (n < NN) ? *(const float4*)&h[n * 128 + kq]
                        : make_float4(0.f, 0.f, 0.f, 0.f);
    float4 sc = *(const float4*)&scale[kq];
    float4 sh = *(const float4*)&shift[kq];
    As[(kq + 0) * 68 + node] = fmaxf(v.x * sc.x + sh.x, 0.f);
    As[(kq + 1) * 68 + node] = fmaxf(v.y * sc.y + sh.y, 0.f);
    As[(kq + 2) * 68 + node] = fmaxf(v.z * sc.z + sh.z, 0.f);
    As[(kq + 3) * 68 + node] = fmaxf(v.w * sc.w + sh.w, 0.f);
  }
  float acc[8][8];
#pragma unroll
  for (int i = 0; i < 8; ++i)
#pragma unroll
    for (int m = 0; m < 8; ++m) acc[i][m] = 0.f;

  for (int k0 = 0; k0 < 128; k0 += 16) {
    __syncthreads();
#pragma unroll
    for (int it = 0; it < 4; ++it) {  // B: 16 x 256 = 1024 float4
      int fid = tid + 256 * it;
      int kk = fid >> 6, j4 = (fid & 63) << 2;
      const float* Bsrc = (j4 < 128) ? &Wrel[(k0 + kk) * 128 + j4]
                                     : &Wroot[(k0 + kk) * 128 + (j4 - 128)];
      *(float4*)&Bs[kk * 256 + j4] = *(const float4*)Bsrc;
    }
    __syncthreads();
#pragma unroll 4
    for (int kk = 0; kk < 16; ++kk) {
      float a[8], b[8];
      *(float4*)&a[0] = *(const float4*)&As[(k0 + kk) * 68 + ty * 8];
      *(float4*)&a[4] = *(const float4*)&As[(k0 + kk) * 68 + ty * 8 + 4];
#pragma unroll
      for (int m = 0; m < 8; ++m) b[m] = Bs[kk * 256 + tx + 32 * m];
#pragma unroll
      for (int i = 0; i < 8; ++i)
#pragma unroll
        for (int m = 0; m < 8; ++m) acc[i][m] += a[i] * b[m];
    }
  }
#pragma unroll
  for (int i = 0; i < 8; ++i) {
    int n = nb + ty * 8 + i;
    if (n < NN) {
      yb[n * 64 + tx]      = pack_bf16(acc[i][0], acc[i][1]);
      yb[n * 64 + tx + 32] = pack_bf16(acc[i][2], acc[i][3]);
      float* hp = h + n * 128;
      hp[tx]      = acc[i][4];
      hp[tx + 32] = acc[i][5];
      hp[tx + 64] = acc[i][6];
      hp[tx + 96] = acc[i][7];
    }
  }
}

// h[n] += sum over incoming edges of unpack(yb[src]). 16 lanes/node, uint4/lane.
__global__ __launch_bounds__(256) void k_gather2(
    const u32* __restrict__ yb, const int* __restrict__ csr,
    const int* __restrict__ cur, const int* __restrict__ deg,
    float* __restrict__ h) {
  int tid = blockIdx.x * 256 + threadIdx.x;
  int n = tid >> 4;
  int L = tid & 15;
  int base = L << 2;                              // u32 positions 4L..4L+3
  int c0 = (base & 31) + ((base >> 5) << 6);      // lo-channel base
  int end = cur[n];
  int i = end - deg[n];
  float lo0 = 0.f, lo1 = 0.f, lo2 = 0.f, lo3 = 0.f;
  float hi0 = 0.f, hi1 = 0.f, hi2 = 0.f, hi3 = 0.f;
  for (; i < end; ++i) {
    int s = csr[i];
    uint4 v = *(const uint4*)&yb[s * 64 + base];
    lo0 += __uint_as_float(v.x << 16); hi0 += __uint_as_float(v.x & 0xffff0000u);
    lo1 += __uint_as_float(v.y << 16); hi1 += __uint_as_float(v.y & 0xffff0000u);
    lo2 += __uint_as_float(v.z << 16); hi2 += __uint_as_float(v.z & 0xffff0000u);
    lo3 += __uint_as_float(v.w << 16); hi3 += __uint_as_float(v.w & 0xffff0000u);
  }
  float4 A = *(const float4*)&h[n * 128 + c0];
  float4 B = *(const float4*)&h[n * 128 + c0 + 32];
  *(float4*)&h[n * 128 + c0] =
      make_float4(A.x + lo0, A.y + lo1, A.z + lo2, A.w + lo3);
  *(float4*)&h[n * 128 + c0 + 32] =
      make_float4(B.x + hi0, B.y + hi1, B.z + hi2, B.w + hi3);
}

__global__ __launch_bounds__(256) void k_final(
    const float* __restrict__ h, const float* __restrict__ scale,
    const float* __restrict__ shift, float* __restrict__ out) {
  int tid = blockIdx.x * 256 + threadIdx.x;
  int base = tid << 2;
  int f4 = base & 127;
  float4 v = *(const float4*)&h[base];
  float4 sc = *(const float4*)&scale[f4];
  float4 sh = *(const float4*)&shift[f4];
  *(float4*)&out[base] = make_float4(v.x * sc.x + sh.x, v.y * sc.y + sh.y,
                                     v.z * sc.z + sh.z, v.w * sc.w + sh.w);
}

extern "C" void kernel_launch(void* const* d_in, const int* in_sizes, int n_in,
                              void* d_out, int out_size, void* d_ws, size_t ws_size,
                              hipStream_t stream) {
  if (ws_size < WS_NEEDED) {
    k_fallback<<<(NN * 128 + 255) / 256, 256, 0, stream>>>((float*)d_out);
    return;
  }
  const float* x      = (const float*)d_in[0];
  const int*   ei     = (const int*)d_in[1];
  const float* Wrel0  = (const float*)d_in[2];
  // d_in[3] = b_rel0: per-channel constant pre-BN -> cancels in BN, unused
  const float* Wroot0 = (const float*)d_in[4];
  const float* gamma0 = (const float*)d_in[5];
  const float* beta0  = (const float*)d_in[6];
  const float* Wrel1  = (const float*)d_in[7];
  // d_in[8] = b_rel1: unused (cancels in BN)
  const float* Wroot1 = (const float*)d_in[9];
  const float* gamma1 = (const float*)d_in[10];
  const float* beta1  = (const float*)d_in[11];

  float* aggx = (float*)d_ws;          // NN*64 (reused as yb after gemm_a)
  u32*   yb   = (u32*)d_ws;
  float* st   = aggx + NN * 64;        // 1024 floats
  float* scale0 = st;       float* shift0 = st + 128;
  float* scale1 = st + 256; float* shift1 = st + 384;
  int* mode = (int*)(st + 512);
  int* deg = (int*)(st + 1024);        // NN
  int* cur = deg + NN;                 // NN
  int* csr = cur + NN;                 // NE
  float* psum = (float*)(csr + NE);    // 256*128
  float* pssq = psum + 32768;          // 256*128
  float* h = (float*)d_out;            // h lives in d_out; k_final is in-place

  hipMemsetAsync(deg, 0, (size_t)NN * 4, stream);
  k_detect<<<1, 64, 0, stream>>>(ei, mode);
  k_hist<<<NE / 256, 256, 0, stream>>>(ei, mode, deg);
  k_scan<<<1, 1024, 0, stream>>>(deg, cur);
  k_place<<<NE / 256, 256, 0, stream>>>(ei, mode, cur, csr);

  k_gather_x<<<(NN * 16) / 256, 256, 0, stream>>>(x, csr, cur, deg, aggx);
  k_gemm_a<<<(NN + 127) / 128, 256, 0, stream>>>(x, aggx, Wrel0, Wroot0, h);
  k_stats_part<<<256, 256, 0, stream>>>(h, psum, pssq);
  k_bnfin<<<1, 128, 0, stream>>>(psum, pssq, gamma0, beta0, scale0, shift0);
  k_gemm_b<<<(NN + 63) / 64, 256, 0, stream>>>(Wrel1, Wroot1, scale0, shift0, yb, h);
  k_gather2<<<(NN * 16) / 256, 256, 0, stream>>>(yb, csr, cur, deg, h);
  k_stats_part<<<256, 256, 0, stream>>>(h, psum, pssq);
  k_bnfin<<<1, 128, 0, stream>>>(psum, pssq, gamma1, beta1, scale1, shift1);
  k_final<<<(NN * 128) / 1024, 256, 0, stream>>>(h, scale1, shift1, (float*)d_out);
}